// Round 5
// baseline (645.088 us; speedup 1.0000x reference)
//
#include <hip/hip_runtime.h>

// Caps layer: B=256 batches, S=512 input caps, D=256 in-dim, NC=16, DC=32, O=512.
// One block per batch; grid 256 = 1 block/CU (structural).
// R5 change: defeat the RA's occupancy heuristic via LDS, not attributes.
// R2/R3/R4 all produced VGPR_Count=64 + ~420 MB scratch spill: the backend
// derives its occupancy target from LDS (43.5 KB -> 3 blocks -> clamp 32
// waves/CU -> 8 waves/EU -> 64-VGPR budget) and every waves-per-EU hint
// (__launch_bounds__ 2nd arg, bare, amdgpu_waves_per_eu) failed to lower it.
// Padding LDS to 82,432 B (> 163840/2) makes the backend's own calc yield
// 1 block/CU = 16 waves = 4 waves/EU -> 128-VGPR budget; acc[16][4] fits
// (~124 regs, proven in R1). Pad array kept alive by asm address-escape.
// Free at runtime: grid=256 means there was never a 2nd block per CU.
// Factorized routing (u_hat never materialized):
//   y[n][D]   = sum_s c[n][s] x[s][D]
//   outputs   = squash_d( y[n] . W[:, n*32+d] )
//   z[n][D]   = sum_d W[D][n*32+d] outputs[n][d]
//   b[n][s]   = sum_D x[s][D] z[n][D]           (MFMA 16x16x32 bf16, fp32 acc)

#define S_ 512
#define D_ 256
#define O_ 512

typedef __attribute__((ext_vector_type(8))) short short8;
typedef __attribute__((ext_vector_type(4))) float floatx4;

__device__ __forceinline__ unsigned short f2b(float f) {
  union { float ff; unsigned int i; } v; v.ff = f;
  unsigned int u = v.i;
  return (unsigned short)((u + 0x7FFFu + ((u >> 16) & 1u)) >> 16);
}

__global__ __launch_bounds__(1024) void caps_kernel(
    const float* __restrict__ x, const float* __restrict__ W,
    float* __restrict__ out)
{
  // LDS (82432 B total = 43520 live + 38912 pad):
  //   ytmp f32 16x260 = 16640 B: y[n][D] (atomicAdd accumulated in iters 1,2)
  //   zb   u16 16x264 =  8448 B: z bf16 (528 B rows, MFMA A-frag source)
  //   outp f32 512    =  2048 B
  //   cbuf f32 16x256 = 16384 B: per-wave c-tile [16n][16s]; iter-0 rowsum
  //                              strips; squash-pass partial sums
  //   lds_pad         = 38912 B: occupancy control (see header comment)
  __shared__ __align__(16) float ytmp[16 * 260];
  __shared__ __align__(16) unsigned short zb[16 * 264];
  __shared__ __align__(16) float outp[O_];
  __shared__ __align__(16) float cbuf[16 * 256];
  __shared__ __align__(16) float lds_pad[9728];

  // Address-escape keeps lds_pad allocated (costs one v_mov).
  {
    unsigned pp = (unsigned)(size_t)lds_pad;
    asm volatile("" : : "v"(pp));
  }

  const int tid  = threadIdx.x;
  const int wave = tid >> 6;
  const int lane = tid & 63;
  const int l15  = lane & 15;
  const int l4   = lane >> 4;
  const float* xb = x + (size_t)blockIdx.x * (S_ * D_);

  for (int it = 0; it < 3; ++it) {
    if (it == 0) {
      // ---- iter 0: b=0 -> c=1/16 uniform -> y[n][:] = (1/16)*rowsum(x) ----
      float a0 = 0.f, a1 = 0.f, a2 = 0.f, a3 = 0.f;
      #pragma unroll 4
      for (int r = 0; r < 32; ++r) {
        const int s = (wave << 5) + r;
        const float4 xv = *(const float4*)(xb + s * D_ + (lane << 2));
        a0 += xv.x; a1 += xv.y; a2 += xv.z; a3 += xv.w;
      }
      *(float4*)(cbuf + (wave << 8) + (lane << 2)) = make_float4(a0, a1, a2, a3);
      __syncthreads();
      if (tid < 256) {
        float v = 0.f;
        #pragma unroll
        for (int w = 0; w < 16; ++w) v += cbuf[(w << 8) + tid];
        v *= 0.0625f;
        #pragma unroll
        for (int n = 0; n < 16; ++n) ytmp[n * 260 + tid] = v;
      }
      __syncthreads();
    } else {
      // ---- FUSED pass: per 16-s subtile: b-tile MFMA -> softmax -> y-acc ----
      float acc[16][4];
      #pragma unroll
      for (int n = 0; n < 16; ++n) { acc[n][0]=0.f; acc[n][1]=0.f; acc[n][2]=0.f; acc[n][3]=0.f; }
      float* cw = cbuf + (wave << 8);   // wave-private c-tile [16n][16s]

      #pragma unroll 1
      for (int t = 0; t < 2; ++t) {
        const int s0 = (wave << 5) + (t << 4);
        // b-tile: b[16n x 16s] = z[16x256] * x^T[256x16]; fp32 acc
        floatx4 C = {0.f, 0.f, 0.f, 0.f};
        #pragma unroll
        for (int k = 0; k < 8; ++k) {
          // A-frag: z[m=l15][k*32 + l4*8 + j] from LDS (528 B rows, 16B-aligned)
          const short8 A = *(const short8*)(zb + l15 * 264 + (k << 5) + (l4 << 3));
          // B-frag: x[s0+l15][k*32 + l4*8 + j] fp32 global -> bf16
          const float* xp = xb + (s0 + l15) * D_ + (k << 5) + (l4 << 3);
          const float4 xv0 = *(const float4*)xp;
          const float4 xv1 = *(const float4*)(xp + 4);
          short8 Bf;
          Bf[0] = (short)f2b(xv0.x); Bf[1] = (short)f2b(xv0.y);
          Bf[2] = (short)f2b(xv0.z); Bf[3] = (short)f2b(xv0.w);
          Bf[4] = (short)f2b(xv1.x); Bf[5] = (short)f2b(xv1.y);
          Bf[6] = (short)f2b(xv1.z); Bf[7] = (short)f2b(xv1.w);
          C = __builtin_amdgcn_mfma_f32_16x16x32_bf16(A, Bf, C, 0, 0, 0);
        }
        // C/D layout: col = l15 (s), row = l4*4 + rg (n).
        // softmax over n: 4 regs local + reduce across l4 (lanes ^16, ^32)
        float m = fmaxf(fmaxf(C[0], C[1]), fmaxf(C[2], C[3]));
        m = fmaxf(m, __shfl_xor(m, 16, 64));
        m = fmaxf(m, __shfl_xor(m, 32, 64));
        const float e0 = __expf(C[0] - m), e1 = __expf(C[1] - m);
        const float e2 = __expf(C[2] - m), e3 = __expf(C[3] - m);
        float sm = e0 + e1 + e2 + e3;
        sm += __shfl_xor(sm, 16, 64);
        sm += __shfl_xor(sm, 32, 64);
        const float inv = 1.f / sm;
        const int nb = l4 << 2;
        cw[(nb + 0) * 16 + l15] = e0 * inv;
        cw[(nb + 1) * 16 + l15] = e1 * inv;
        cw[(nb + 2) * 16 + l15] = e2 * inv;
        cw[(nb + 3) * 16 + l15] = e3 * inv;
        // same-wave LDS RAW: drain writes; "memory" clobber pins ordering
        asm volatile("s_waitcnt lgkmcnt(0)" ::: "memory");
        // y-acc: lane owns D-quad; x tile re-read is L1/L2-hot (just fetched).
        // Per-n c4 loads keep the live set small (128-VGPR cap at 4 waves/SIMD).
        #pragma unroll 1
        for (int g = 0; g < 4; ++g) {
          const float4 xv0g = *(const float4*)(xb + (s0 + (g << 2) + 0) * D_ + (lane << 2));
          const float4 xv1g = *(const float4*)(xb + (s0 + (g << 2) + 1) * D_ + (lane << 2));
          const float4 xv2g = *(const float4*)(xb + (s0 + (g << 2) + 2) * D_ + (lane << 2));
          const float4 xv3g = *(const float4*)(xb + (s0 + (g << 2) + 3) * D_ + (lane << 2));
          #pragma unroll
          for (int n = 0; n < 16; ++n) {
            const float4 c4 = *(const float4*)(cw + n * 16 + (g << 2));  // wave-uniform b128
            acc[n][0] += c4.x * xv0g.x; acc[n][1] += c4.x * xv0g.y;
            acc[n][2] += c4.x * xv0g.z; acc[n][3] += c4.x * xv0g.w;
            acc[n][0] += c4.y * xv1g.x; acc[n][1] += c4.y * xv1g.y;
            acc[n][2] += c4.y * xv1g.z; acc[n][3] += c4.y * xv1g.w;
            acc[n][0] += c4.z * xv2g.x; acc[n][1] += c4.z * xv2g.y;
            acc[n][2] += c4.z * xv2g.z; acc[n][3] += c4.z * xv2g.w;
            acc[n][0] += c4.w * xv3g.x; acc[n][1] += c4.w * xv3g.y;
            acc[n][2] += c4.w * xv3g.z; acc[n][3] += c4.w * xv3g.w;
          }
        }
      }
      // accumulate into ytmp: LDS atomics, no barriers, no serialized rounds
      #pragma unroll
      for (int n = 0; n < 16; ++n) {
        atomicAdd(&ytmp[n * 260 + (lane << 2) + 0], acc[n][0]);
        atomicAdd(&ytmp[n * 260 + (lane << 2) + 1], acc[n][1]);
        atomicAdd(&ytmp[n * 260 + (lane << 2) + 2], acc[n][2]);
        atomicAdd(&ytmp[n * 260 + (lane << 2) + 3], acc[n][3]);
      }
      __syncthreads();
    }

    // ---- outputs[n][d] = sum_D y[n][D] * W[D][n*32+d], then squash over d ----
    // D-reduction split across thread pairs: tid does Db 0..15, tid+512 does 16..31.
    {
      const int o = tid & 511;
      const int p = tid >> 9;
      const int n = o >> 5;
      float a = 0.f;
      #pragma unroll 4
      for (int i = 0; i < 16; ++i) {
        const int Db = (p << 4) + i;
        const float4 y0 = *(const float4*)(ytmp + n * 260 + (Db << 3));
        const float4 y1 = *(const float4*)(ytmp + n * 260 + (Db << 3) + 4);
        const float* wp = W + (size_t)(Db << 3) * O_ + o;   // coalesced over o
        a += y0.x * wp[0 * O_]; a += y0.y * wp[1 * O_];
        a += y0.z * wp[2 * O_]; a += y0.w * wp[3 * O_];
        a += y1.x * wp[4 * O_]; a += y1.y * wp[5 * O_];
        a += y1.z * wp[6 * O_]; a += y1.w * wp[7 * O_];
      }
      if (p) cbuf[o] = a;
      __syncthreads();
      if (!p) {
        a += cbuf[o];
        float ss = a * a;
        #pragma unroll
        for (int off = 1; off < 32; off <<= 1) ss += __shfl_xor(ss, off, 64);
        const float v = a / sqrtf(ss + 1e-7f);
        outp[o] = v;
        if (it == 2) out[(size_t)blockIdx.x * O_ + o] = v;
      }
    }
    __syncthreads();

    if (it < 2) {
      // ---- z[n][D] = sum_d W[D][n*32+d] * outputs[n][d]; wave owns 16 D-rows ----
      {
        const int obase = lane << 3;
        const int n_ln  = lane >> 2;
        float ov[8];
        #pragma unroll
        for (int j = 0; j < 8; ++j) ov[j] = outp[obase + j];
        for (int r = 0; r < 16; ++r) {
          const int Dd = (wave << 4) + r;
          const float4 w0 = *(const float4*)(W + (size_t)Dd * O_ + obase);
          const float4 w1 = *(const float4*)(W + (size_t)Dd * O_ + obase + 4);
          float a = w0.x * ov[0] + w0.y * ov[1] + w0.z * ov[2] + w0.w * ov[3]
                  + w1.x * ov[4] + w1.y * ov[5] + w1.z * ov[6] + w1.w * ov[7];
          a += __shfl_xor(a, 1, 64);
          a += __shfl_xor(a, 2, 64);
          if ((lane & 3) == 0) zb[n_ln * 264 + Dd] = f2b(a);
        }
      }
      // zero ytmp for the next iteration's atomic accumulation (free: overlaps z)
      for (int i = tid; i < 16 * 260; i += 1024) ytmp[i] = 0.f;
      __syncthreads();
    }
  }
}

extern "C" void kernel_launch(void* const* d_in, const int* in_sizes, int n_in,
                              void* d_out, int out_size, void* d_ws, size_t ws_size,
                              hipStream_t stream) {
  const float* x = (const float*)d_in[0];   // [256, 512, 256] f32
  const float* W = (const float*)d_in[1];   // [256, 512] f32
  float* out = (float*)d_out;               // [256*512] f32
  (void)in_sizes; (void)n_in; (void)out_size; (void)d_ws; (void)ws_size;
  caps_kernel<<<256, 1024, 0, stream>>>(x, W, out);
}

// Round 6
// 291.099 us; speedup vs baseline: 2.2160x; 2.2160x over previous
//
#include <hip/hip_runtime.h>

// Caps layer: B=256 batches, S=512 input caps, D=256 in-dim, NC=16, DC=32, O=512.
// One block per batch; grid 256 = 1 block/CU (structural). 512 thr, 8 waves.
// R6 change: y-pass moved from VALU f32 to MFMA with EXACT split-bf16 math.
// R2-R5 showed the 1024-thread allocator pins a 64-VGPR budget and spills the
// f32 acc[16][4] (420+ MB scratch). Instead of fighting the RA, remove the
// register hog: y[16n][256D] = c[16x512] * x[512x256] is MFMA-shaped (K=512).
// Precision: c and x each split into bf16 hi+lo (v = hi + lo, RNE); accumulate
// ch*xh + ch*xl + cl*xh in f32 (drop cl*xl <= 2^-18 rel) -> y error ~1e-5,
// absmax stays dominated by the existing bf16 b-path (~0.0039).
// x staged per 32-s chunk into LDS TRANSPOSED xT[d][s] (rows padded to 40 u16,
// 16B-aligned ds_read_b128 B-frags), double-buffered, 1 barrier/chunk.
// Accumulator is now 2 C-frags (8 VGPRs) -> back to 512 thr launch_bounds(512,2)
// where the allocator behaves (R1: 124 VGPR, no spill).
// Factorized routing (u_hat never materialized):
//   y[n][D]   = sum_s c[n][s] x[s][D]            (MFMA, split-bf16, f32 acc)
//   outputs   = squash_d( y[n] . W[:, n*32+d] )
//   z[n][D]   = sum_d W[D][n*32+d] outputs[n][d]
//   b[n][s]   = sum_D x[s][D] z[n][D]            (MFMA 16x16x32 bf16, f32 acc)

#define S_ 512
#define D_ 256
#define O_ 512

typedef __attribute__((ext_vector_type(8))) short short8;
typedef __attribute__((ext_vector_type(4))) float floatx4;

__device__ __forceinline__ unsigned short f2b(float f) {
  union { float ff; unsigned int i; } v; v.ff = f;
  unsigned int u = v.i;
  return (unsigned short)((u + 0x7FFFu + ((u >> 16) & 1u)) >> 16);
}
__device__ __forceinline__ float b2f(unsigned short h) {
  union { unsigned int i; float ff; } v; v.i = ((unsigned int)h) << 16;
  return v.ff;
}

__global__ __launch_bounds__(512, 2) void caps_kernel(
    const float* __restrict__ x, const float* __restrict__ W,
    float* __restrict__ out)
{
  // LDS (144384 B):
  //   xT  u16 [2buf][2 hi/lo][256 d][40 s-pad] = 81920 B: x chunk, transposed,
  //        rows 80 B (16B-aligned b128 reads, ~2-way banks); iter-0 rowsum alias
  //   cds u16 [2 hi/lo][16 n][552 s-pad]       = 35328 B: c split-bf16
  //   ytmp f32 16x260                          = 16640 B: y[n][D]
  //   zb   u16 16x264                          =  8448 B: z bf16 (A-frag source)
  //   outp f32 512                             =  2048 B
  __shared__ __align__(16) unsigned short xT[2][2][256][40];
  __shared__ __align__(16) unsigned short cds[2][16][552];
  __shared__ __align__(16) float ytmp[16 * 260];
  __shared__ __align__(16) unsigned short zb[16 * 264];
  __shared__ __align__(16) float outp[O_];

  const int tid  = threadIdx.x;
  const int wave = tid >> 6;
  const int lane = tid & 63;
  const int l15  = lane & 15;
  const int l4   = lane >> 4;
  const float* xb = x + (size_t)blockIdx.x * (S_ * D_);

  for (int it = 0; it < 3; ++it) {
    if (it == 0) {
      // ---- iter 0: b=0 -> c=1/16 uniform -> y[n][:] = (1/16)*rowsum(x) ----
      float a0 = 0.f, a1 = 0.f, a2 = 0.f, a3 = 0.f;
      #pragma unroll 4
      for (int r = 0; r < 64; ++r) {
        const int s = (wave << 6) + r;
        const float4 xv = *(const float4*)(xb + s * D_ + (lane << 2));
        a0 += xv.x; a1 += xv.y; a2 += xv.z; a3 += xv.w;
      }
      float* rs = (float*)xT;   // alias: 8 waves x 256 f32 strips (8 KB)
      *(float4*)(rs + (wave << 8) + (lane << 2)) = make_float4(a0, a1, a2, a3);
      __syncthreads();
      if (tid < 256) {
        float v = 0.f;
        #pragma unroll
        for (int w = 0; w < 8; ++w) v += rs[(w << 8) + tid];
        v *= 0.0625f;
        #pragma unroll
        for (int n = 0; n < 16; ++n) ytmp[n * 260 + tid] = v;
      }
      __syncthreads();
    } else {
      // ---- Phase A: b-tile MFMA + softmax -> c split-bf16 to LDS ----
      #pragma unroll 1
      for (int t = 0; t < 4; ++t) {
        const int s0 = (wave << 6) + (t << 4);
        floatx4 C = {0.f, 0.f, 0.f, 0.f};
        #pragma unroll
        for (int k = 0; k < 8; ++k) {
          // A-frag: z[m=l15][k*32 + l4*8 + j] from LDS
          const short8 A = *(const short8*)(zb + l15 * 264 + (k << 5) + (l4 << 3));
          // B-frag: x[s0+l15][k*32 + l4*8 + j] fp32 global -> bf16
          const float* xp = xb + (s0 + l15) * D_ + (k << 5) + (l4 << 3);
          const float4 xv0 = *(const float4*)xp;
          const float4 xv1 = *(const float4*)(xp + 4);
          short8 Bf;
          Bf[0] = (short)f2b(xv0.x); Bf[1] = (short)f2b(xv0.y);
          Bf[2] = (short)f2b(xv0.z); Bf[3] = (short)f2b(xv0.w);
          Bf[4] = (short)f2b(xv1.x); Bf[5] = (short)f2b(xv1.y);
          Bf[6] = (short)f2b(xv1.z); Bf[7] = (short)f2b(xv1.w);
          C = __builtin_amdgcn_mfma_f32_16x16x32_bf16(A, Bf, C, 0, 0, 0);
        }
        // C/D layout: col = l15 (s), row = l4*4 + rg (n).
        float m = fmaxf(fmaxf(C[0], C[1]), fmaxf(C[2], C[3]));
        m = fmaxf(m, __shfl_xor(m, 16, 64));
        m = fmaxf(m, __shfl_xor(m, 32, 64));
        const float e0 = __expf(C[0] - m), e1 = __expf(C[1] - m);
        const float e2 = __expf(C[2] - m), e3 = __expf(C[3] - m);
        float sm = e0 + e1 + e2 + e3;
        sm += __shfl_xor(sm, 16, 64);
        sm += __shfl_xor(sm, 32, 64);
        const float inv = 1.f / sm;
        const int nb = l4 << 2;
        const int sc = s0 + l15;
        float vs[4] = {e0 * inv, e1 * inv, e2 * inv, e3 * inv};
        #pragma unroll
        for (int rg = 0; rg < 4; ++rg) {
          const float v = vs[rg];
          const unsigned short ch = f2b(v);
          const unsigned short cl = f2b(v - b2f(ch));
          cds[0][nb + rg][sc] = ch;
          cds[1][nb + rg][sc] = cl;
        }
      }
      __syncthreads();

      // ---- Phase B: y = c * x via MFMA; x staged per 32-s chunk, dbuf ----
      floatx4 CA = {0.f, 0.f, 0.f, 0.f};
      floatx4 CB = {0.f, 0.f, 0.f, 0.f};
      const int dA = wave << 4;          // tile cols 0..127
      const int dB = (wave + 8) << 4;    // tile cols 128..255
      const int d_st = tid & 255;        // staging: thread owns one d column
      const int s0l  = (tid >> 8) << 4;  // and a 16-s half of the chunk
      #pragma unroll 1
      for (int kc = 0; kc < 16; ++kc) {
        const int buf = kc & 1;
        {
          const float* xs = xb + (size_t)((kc << 5) + s0l) * D_ + d_st;
          short8 hv0, hv1, lv0, lv1;
          #pragma unroll
          for (int j = 0; j < 8; ++j) {
            const float v = xs[j * D_];
            const unsigned short h = f2b(v);
            hv0[j] = (short)h; lv0[j] = (short)f2b(v - b2f(h));
          }
          #pragma unroll
          for (int j = 0; j < 8; ++j) {
            const float v = xs[(j + 8) * D_];
            const unsigned short h = f2b(v);
            hv1[j] = (short)h; lv1[j] = (short)f2b(v - b2f(h));
          }
          *(short8*)&xT[buf][0][d_st][s0l]     = hv0;
          *(short8*)&xT[buf][0][d_st][s0l + 8] = hv1;
          *(short8*)&xT[buf][1][d_st][s0l]     = lv0;
          *(short8*)&xT[buf][1][d_st][s0l + 8] = lv1;
        }
        __syncthreads();   // stage(kc) done; dbuf makes 1 barrier/chunk safe
        // A-frag: c[n=l15][kc*32 + l4*8 + j]; B-frag: xT[d=col][s=l4*8+j]
        const short8 Ah  = *(const short8*)&cds[0][l15][(kc << 5) + (l4 << 3)];
        const short8 Al  = *(const short8*)&cds[1][l15][(kc << 5) + (l4 << 3)];
        const short8 BAh = *(const short8*)&xT[buf][0][dA + l15][l4 << 3];
        const short8 BAl = *(const short8*)&xT[buf][1][dA + l15][l4 << 3];
        const short8 BBh = *(const short8*)&xT[buf][0][dB + l15][l4 << 3];
        const short8 BBl = *(const short8*)&xT[buf][1][dB + l15][l4 << 3];
        CA = __builtin_amdgcn_mfma_f32_16x16x32_bf16(Ah, BAh, CA, 0, 0, 0);
        CA = __builtin_amdgcn_mfma_f32_16x16x32_bf16(Ah, BAl, CA, 0, 0, 0);
        CA = __builtin_amdgcn_mfma_f32_16x16x32_bf16(Al, BAh, CA, 0, 0, 0);
        CB = __builtin_amdgcn_mfma_f32_16x16x32_bf16(Ah, BBh, CB, 0, 0, 0);
        CB = __builtin_amdgcn_mfma_f32_16x16x32_bf16(Ah, BBl, CB, 0, 0, 0);
        CB = __builtin_amdgcn_mfma_f32_16x16x32_bf16(Al, BBh, CB, 0, 0, 0);
      }
      // C/D layout: col = l15 (d within tile), row = l4*4 + rg (n)
      #pragma unroll
      for (int rg = 0; rg < 4; ++rg)
        ytmp[((l4 << 2) + rg) * 260 + dA + l15] = CA[rg];
      #pragma unroll
      for (int rg = 0; rg < 4; ++rg)
        ytmp[((l4 << 2) + rg) * 260 + dB + l15] = CB[rg];
      __syncthreads();
    }

    // ---- outputs[n][d] = sum_D y[n][D] * W[D][n*32+d], then squash over d ----
    {
      const int o = tid;
      const int n = o >> 5;
      float a = 0.f;
      for (int Db = 0; Db < 32; ++Db) {
        const float4 y0 = *(const float4*)(ytmp + n * 260 + (Db << 3));
        const float4 y1 = *(const float4*)(ytmp + n * 260 + (Db << 3) + 4);
        const float* wp = W + (size_t)(Db << 3) * O_ + o;   // coalesced over o
        a += y0.x * wp[0 * O_]; a += y0.y * wp[1 * O_];
        a += y0.z * wp[2 * O_]; a += y0.w * wp[3 * O_];
        a += y1.x * wp[4 * O_]; a += y1.y * wp[5 * O_];
        a += y1.z * wp[6 * O_]; a += y1.w * wp[7 * O_];
      }
      float ss = a * a;
      #pragma unroll
      for (int off = 1; off < 32; off <<= 1) ss += __shfl_xor(ss, off, 64);
      const float v = a / sqrtf(ss + 1e-7f);
      outp[o] = v;
      if (it == 2) out[(size_t)blockIdx.x * O_ + o] = v;
    }
    __syncthreads();

    if (it < 2) {
      // ---- z[n][D] = sum_d W[D][n*32+d] * outputs[n][d]; wave owns 32 D-rows ----
      {
        const int obase = lane << 3;
        const int n_ln  = lane >> 2;
        float ov[8];
        #pragma unroll
        for (int j = 0; j < 8; ++j) ov[j] = outp[obase + j];
        for (int r = 0; r < 32; ++r) {
          const int Dd = (wave << 5) + r;
          const float4 w0 = *(const float4*)(W + (size_t)Dd * O_ + obase);
          const float4 w1 = *(const float4*)(W + (size_t)Dd * O_ + obase + 4);
          float a = w0.x * ov[0] + w0.y * ov[1] + w0.z * ov[2] + w0.w * ov[3]
                  + w1.x * ov[4] + w1.y * ov[5] + w1.z * ov[6] + w1.w * ov[7];
          a += __shfl_xor(a, 1, 64);
          a += __shfl_xor(a, 2, 64);
          if ((lane & 3) == 0) zb[n_ln * 264 + Dd] = f2b(a);
        }
      }
      __syncthreads();
    }
  }
}

extern "C" void kernel_launch(void* const* d_in, const int* in_sizes, int n_in,
                              void* d_out, int out_size, void* d_ws, size_t ws_size,
                              hipStream_t stream) {
  const float* x = (const float*)d_in[0];   // [256, 512, 256] f32
  const float* W = (const float*)d_in[1];   // [256, 512] f32
  float* out = (float*)d_out;               // [256*512] f32
  (void)in_sizes; (void)n_in; (void)out_size; (void)d_ws; (void)ws_size;
  caps_kernel<<<256, 512, 0, stream>>>(x, W, out);
}